// Round 12
// baseline (1448.473 us; speedup 1.0000x reference)
//
#include <hip/hip_runtime.h>

#define TPB 256

static constexpr int B_ = 4;
static constexpr int DEG_ = 16;

using u16 = unsigned short;

// level bases into the packed count array (sum = 87040 = 85 * 1024)
static constexpr int LB0 = 0, LB1 = 65536, LB2 = 81920, LB3 = 86016, LB4 = 87040;
// cumulative edge counts
static constexpr int CE0 = 0, CE1 = 1048576, CE2 = 1310720, CE3 = 1376256, CE4 = 1392640;

// ---------------- bf16 helpers ----------------

__device__ inline float b2f(u16 u) { return __uint_as_float((unsigned)u << 16); }
__device__ inline u16 f2b(float f) {
    unsigned b = __float_as_uint(f);
    b += 0x7fffu + ((b >> 16) & 1u);   // round-to-nearest-even
    return (u16)(b >> 16);
}

template<int F>
__device__ inline void load_row_bf16(const u16* __restrict__ p, float* v) {
    if constexpr (F % 8 == 0) {
        #pragma unroll
        for (int i = 0; i < F / 8; ++i) {
            uint4 raw = reinterpret_cast<const uint4*>(p)[i];
            unsigned rr[4] = {raw.x, raw.y, raw.z, raw.w};
            #pragma unroll
            for (int k = 0; k < 4; ++k) {
                v[i * 8 + 2 * k]     = __uint_as_float(rr[k] << 16);
                v[i * 8 + 2 * k + 1] = __uint_as_float(rr[k] & 0xffff0000u);
            }
        }
    } else {
        #pragma unroll
        for (int f = 0; f < F; ++f) v[f] = b2f(p[f]);
    }
}

template<int F>
__device__ inline void store_row_bf16(u16* __restrict__ p, const float* v) {
    if constexpr (F % 8 == 0) {
        #pragma unroll
        for (int i = 0; i < F / 8; ++i) {
            uint4 raw;
            unsigned* rr = &raw.x;
            #pragma unroll
            for (int k = 0; k < 4; ++k)
                rr[k] = (unsigned)f2b(v[i * 8 + 2 * k]) |
                        ((unsigned)f2b(v[i * 8 + 2 * k + 1]) << 16);
            reinterpret_cast<uint4*>(p)[i] = raw;
        }
    } else {
        #pragma unroll
        for (int f = 0; f < F; ++f) p[f] = f2b(v[f]);
    }
}

// ---------------- merged CSR build kernels ----------------

__global__ void cnt_all_kernel(const int* __restrict__ r0, const int* __restrict__ r1,
                               const int* __restrict__ r2, const int* __restrict__ r3,
                               int* __restrict__ cntAll) {
    int e = blockIdx.x * blockDim.x + threadIdx.x;
    if (e >= CE4) return;
    const int* rp; int base, lb;
    if (e < CE1)      { rp = r0; base = CE0; lb = LB0; }
    else if (e < CE2) { rp = r1; base = CE1; lb = LB1; }
    else if (e < CE3) { rp = r2; base = CE2; lb = LB2; }
    else              { rp = r3; base = CE3; lb = LB3; }
    atomicAdd(&cntAll[lb + rp[e - base]], 1);
}

__global__ void scanA_kernel(const int* __restrict__ cnt, int* __restrict__ partial,
                             int* __restrict__ bsum) {
    __shared__ int sdata[256];
    int tid = threadIdx.x;
    int base = blockIdx.x * 1024 + tid * 4;
    int v0 = cnt[base], v1 = cnt[base + 1], v2 = cnt[base + 2], v3 = cnt[base + 3];
    int tsum = v0 + v1 + v2 + v3;
    sdata[tid] = tsum;
    __syncthreads();
    for (int ofs = 1; ofs < 256; ofs <<= 1) {
        int x = (tid >= ofs) ? sdata[tid - ofs] : 0;
        __syncthreads();
        sdata[tid] += x;
        __syncthreads();
    }
    int excl = sdata[tid] - tsum;
    partial[base] = excl;         excl += v0;
    partial[base + 1] = excl;     excl += v1;
    partial[base + 2] = excl;     excl += v2;
    partial[base + 3] = excl;
    if (tid == 255) bsum[blockIdx.x] = sdata[255];
}

__global__ void scanB_kernel(int* __restrict__ bsum, int nb) {
    __shared__ int s[128];
    int tid = threadIdx.x;
    int v = tid < nb ? bsum[tid] : 0;
    s[tid] = v;
    __syncthreads();
    for (int ofs = 1; ofs < 128; ofs <<= 1) {
        int x = (tid >= ofs) ? s[tid - ofs] : 0;
        __syncthreads();
        s[tid] += x;
        __syncthreads();
    }
    if (tid < nb) bsum[tid] = s[tid] - v;
}

__global__ void scanC_kernel(const int* __restrict__ partial, const int* __restrict__ bsum,
                             const int* __restrict__ cnt, float* __restrict__ disAll,
                             int* __restrict__ rp0, int* __restrict__ rp1,
                             int* __restrict__ rp2, int* __restrict__ rp3) {
    int i = blockIdx.x * blockDim.x + threadIdx.x;
    if (i >= LB4) return;
    int g = partial[i] + bsum[i >> 10];
    if (i < LB1)      rp0[i - LB0] = g - CE0;
    else if (i < LB2) rp1[i - LB1] = g - CE1;
    else if (i < LB3) rp2[i - LB2] = g - CE2;
    else              rp3[i - LB3] = g - CE3;
    int c = cnt[i];
    disAll[i] = c > 0 ? rsqrtf((float)c) : 0.f;
    if (i == 0) {
        rp0[LB1 - LB0] = CE1 - CE0;
        rp1[LB2 - LB1] = CE2 - CE1;
        rp2[LB3 - LB2] = CE3 - CE2;
        rp3[LB4 - LB3] = CE4 - CE3;
    }
}

__global__ void fill_all_kernel(const int* __restrict__ r0, const int* __restrict__ c0,
                                const int* __restrict__ r1, const int* __restrict__ c1,
                                const int* __restrict__ r2, const int* __restrict__ c2,
                                const int* __restrict__ r3, const int* __restrict__ c3,
                                const int* __restrict__ rp0, const int* __restrict__ rp1,
                                const int* __restrict__ rp2, const int* __restrict__ rp3,
                                int* __restrict__ curAll, u16* __restrict__ ccolAll) {
    int e = blockIdx.x * blockDim.x + threadIdx.x;
    if (e >= CE4) return;
    const int* rowp; const int* colp; const int* rptr; int base, lb;
    if (e < CE1)      { rowp = r0; colp = c0; rptr = rp0; base = CE0; lb = LB0; }
    else if (e < CE2) { rowp = r1; colp = c1; rptr = rp1; base = CE1; lb = LB1; }
    else if (e < CE3) { rowp = r2; colp = c2; rptr = rp2; base = CE2; lb = LB2; }
    else              { rowp = r3; colp = c3; rptr = rp3; base = CE3; lb = LB3; }
    int le = e - base;
    int r = rowp[le];
    int pos = rptr[r] + atomicAdd(&curAll[lb + r], 1);
    ccolAll[base + pos] = (u16)colp[le];
}

// ---------------- fp32 -> bf16 straight convert (lvl0 planar keeps [B][N][3]) ----------

__global__ void f2b_kernel(const float* __restrict__ in, u16* __restrict__ out, int n) {
    int i = blockIdx.x * blockDim.x + threadIdx.x;
    if (i < n) out[i] = f2b(in[i]);
}

// ---------------- lvl0 Chebyshev T-sweep: batch-planar + XCD pinning ----------------
// Features [B][N][F]; batch b runs only on XCD pair {2b,2b+1} (blockIdx round-robins
// XCDs -> b=(blk>>1)&3). Per-batch working set = N*F*2B = 2.1 MB (F=16) -> L2-resident.
template<int F, bool FIRST>
__global__ __launch_bounds__(128) void sweep_p(
    const u16* __restrict__ gsrc, const u16* __restrict__ selfp, u16* __restrict__ dst,
    const int* __restrict__ rowptr, const u16* __restrict__ ccol,
    const float* __restrict__ dis, int N)
{
    int blk = blockIdx.x;
    int b = (blk >> 1) & 3;
    int j = ((blk >> 3) << 1) | (blk & 1);
    int r = j * 128 + (int)threadIdx.x;
    if (r >= N) return;
    size_t t = (size_t)b * N + r;

    float tv[F];
    if constexpr (FIRST) {
        #pragma unroll
        for (int f = 0; f < F; ++f) tv[f] = 0.f;
    } else {
        float sv[F];
        load_row_bf16<F>(selfp + t * F, sv);
        #pragma unroll
        for (int f = 0; f < F; ++f) tv[f] = -sv[f];
    }
    const float scale = (FIRST ? 1.0f : 2.0f) * dis[r];
    const u16* base = gsrc + (size_t)b * N * F;
    int beg = rowptr[r], end = rowptr[r + 1];
    for (int e = beg; e < end; ++e) {
        int c = (int)ccol[e];
        float w = scale * dis[c];
        float gv[F];
        load_row_bf16<F>(base + (size_t)c * F, gv);
        #pragma unroll
        for (int f = 0; f < F; ++f) tv[f] += w * gv[f];
    }
    store_row_bf16<F>(dst + t * F, tv);
}

// ---------------- interleaved sweep for levels 1-3 ([N][B][F]) ----------------
template<int F, bool FIRST>
__global__ __launch_bounds__(128) void sweep_k(
    const u16* __restrict__ gsrc, const u16* __restrict__ selfp, u16* __restrict__ dst,
    const int* __restrict__ rowptr, const u16* __restrict__ ccol,
    const float* __restrict__ dis, int N)
{
    int t = blockIdx.x * 128 + (int)threadIdx.x;
    if (t >= B_ * N) return;
    int r = t >> 2;
    int b = t & 3;

    float tv[F];
    if constexpr (FIRST) {
        #pragma unroll
        for (int f = 0; f < F; ++f) tv[f] = 0.f;
    } else {
        float sv[F];
        load_row_bf16<F>(selfp + (size_t)t * F, sv);
        #pragma unroll
        for (int f = 0; f < F; ++f) tv[f] = -sv[f];
    }
    const float scale = (FIRST ? 1.0f : 2.0f) * dis[r];
    int beg = rowptr[r], end = rowptr[r + 1];
    for (int e = beg; e < end; ++e) {
        int c = (int)ccol[e];
        float w = scale * dis[c];
        float gv[F];
        load_row_bf16<F>(gsrc + (size_t)((c << 2) | b) * F, gv);
        #pragma unroll
        for (int f = 0; f < F; ++f) tv[f] += w * gv[f];
    }
    store_row_bf16<F>(dst + (size_t)t * F, tv);
}

// ---------------- streaming combine: out = sum_k T_k @ W_k (+bias, relu) ----------------
// Row-t semantics, layout agnostic. OSTD: fp32 row write (planar lvl0 == canonical).
template<int F, int G, bool OSTD>
__global__ __launch_bounds__(128) void combine_k(
    const u16* __restrict__ T0, const u16* __restrict__ T1, const u16* __restrict__ T2,
    const u16* __restrict__ T3, const u16* __restrict__ T4, const u16* __restrict__ T5,
    const float* __restrict__ W6, const float* __restrict__ bias,
    u16* __restrict__ outb, float* __restrict__ outf, int N, int relu)
{
    __shared__ float sW[6 * F * G];
    for (int i = threadIdx.x; i < 6 * F * G; i += 128) sW[i] = W6[i];
    __syncthreads();
    int t = blockIdx.x * 128 + (int)threadIdx.x;
    if (t >= B_ * N) return;

    float acc[G];
    #pragma unroll
    for (int g = 0; g < G; ++g) acc[g] = 0.f;

    const u16* Ts[6] = {T0, T1, T2, T3, T4, T5};
    #pragma unroll
    for (int k = 0; k < 6; ++k) {
        float tv[F];
        load_row_bf16<F>(Ts[k] + (size_t)t * F, tv);
        const float* w = sW + k * F * G;
        #pragma unroll
        for (int f = 0; f < F; ++f) {
            float x = tv[f];
            #pragma unroll
            for (int g = 0; g < G; ++g) acc[g] += x * w[f * G + g];
        }
    }
    if (bias) {
        #pragma unroll
        for (int g = 0; g < G; ++g) acc[g] += bias[g];
    }
    if (relu) {
        #pragma unroll
        for (int g = 0; g < G; ++g) acc[g] = fmaxf(acc[g], 0.f);
    }
    if (OSTD) {
        float* orow = outf + (size_t)t * G;
        #pragma unroll
        for (int g = 0; g < G; ++g) orow[g] = acc[g];
    } else {
        store_row_bf16<G>(outb + (size_t)t * G, acc);
    }
}

// ---------------- pools ----------------

// interleaved -> interleaved (levels 1-3 transitions)
__global__ void pool_kernel(const u16* __restrict__ in, u16* __restrict__ out,
                            const int* __restrict__ idx, const float* __restrict__ w,
                            int Nout, int F) {
    int t = blockIdx.x * blockDim.x + threadIdx.x;
    if (t >= B_ * Nout * F) return;
    int f = t % F;
    int nb = t / F;
    int b = nb & 3;
    int n = nb >> 2;
    float acc = 0.f;
    for (int k = 0; k < 3; ++k) {
        int src = idx[n * 3 + k];
        acc += w[n * 3 + k] * b2f(in[(size_t)((src << 2) | b) * F + f]);
    }
    out[t] = f2b(acc);
}

// planar lvl0 -> interleaved lvl1 (down-pool 0)
__global__ void pool_down0(const u16* __restrict__ in, u16* __restrict__ out,
                           const int* __restrict__ idx, const float* __restrict__ w,
                           int Nin, int Nout, int F) {
    int t = blockIdx.x * blockDim.x + threadIdx.x;
    if (t >= B_ * Nout * F) return;
    int f = t % F;
    int nb = t / F;
    int b = nb & 3;
    int n = nb >> 2;
    float acc = 0.f;
    for (int k = 0; k < 3; ++k) {
        int src = idx[n * 3 + k];
        acc += w[n * 3 + k] * b2f(in[((size_t)b * Nin + src) * F + f]);
    }
    out[t] = f2b(acc);
}

// interleaved lvl1 -> planar lvl0 (up-pool 0)
__global__ void pool_up0(const u16* __restrict__ in, u16* __restrict__ out,
                         const int* __restrict__ idx, const float* __restrict__ w,
                         int Nout, int F) {
    int t = blockIdx.x * blockDim.x + threadIdx.x;   // planar order [B][Nout][F]
    if (t >= B_ * Nout * F) return;
    int f = t % F;
    int bn = t / F;
    int n = bn % Nout;
    int b = bn / Nout;
    float acc = 0.f;
    for (int k = 0; k < 3; ++k) {
        int src = idx[n * 3 + k];
        acc += w[n * 3 + k] * b2f(in[(size_t)((src << 2) | b) * F + f]);
    }
    out[t] = f2b(acc);
}

// h bf16 interleaved [256][4][32]; logical h[b, i], i = n*32+f
__global__ void dense_enc_kernel(const u16* __restrict__ h, const float* __restrict__ W,
                                 const float* __restrict__ bias, float* __restrict__ z) {
    int b = blockIdx.x >> 6;
    int g = blockIdx.x & 63;
    int tid = threadIdx.x;
    float acc = 0.f;
    for (int i = tid; i < 8192; i += 256) {
        int n = i >> 5, f = i & 31;
        acc += b2f(h[(((size_t)n << 2) | b) * 32 + f]) * W[(size_t)i * 64 + g];
    }
    __shared__ float red[256];
    red[tid] = acc;
    __syncthreads();
    for (int sft = 128; sft > 0; sft >>= 1) {
        if (tid < sft) red[tid] += red[tid + sft];
        __syncthreads();
    }
    if (tid == 0) z[b * 64 + g] = fmaxf(red[0] + bias[g], 0.f);
}

// out bf16 interleaved [256][4][32]
__global__ void dense_dec_kernel(const float* __restrict__ z, const float* __restrict__ W,
                                 const float* __restrict__ bias, u16* __restrict__ out) {
    int t = blockIdx.x * blockDim.x + threadIdx.x;
    if (t >= B_ * 8192) return;
    int b = t / 8192, j = t % 8192;
    float acc = bias[j];
    for (int k = 0; k < 64; ++k) acc += z[b * 64 + k] * W[(size_t)k * 8192 + j];
    int n = j >> 5, f = j & 31;
    out[(((size_t)n << 2) | b) * 32 + f] = f2b(fmaxf(acc, 0.f));
}

// ---------------- host ----------------

static inline unsigned cdivu(size_t a, size_t b) { return (unsigned)((a + b - 1) / b); }

// interleaved conv (levels 1-3)
template<int F, int G>
static void run_cheb(const u16* X, u16* const* T, const float* Wk, const float* bias,
                     int relu, u16* outb,
                     const int* rp, const u16* cc, const float* dis, int N, hipStream_t s) {
    unsigned g = (unsigned)cdivu((size_t)B_ * N, 128);
    sweep_k<F, true><<<g, 128, 0, s>>>(X, nullptr, T[0], rp, cc, dis, N);
    sweep_k<F, false><<<g, 128, 0, s>>>(T[0], X, T[1], rp, cc, dis, N);
    sweep_k<F, false><<<g, 128, 0, s>>>(T[1], T[0], T[2], rp, cc, dis, N);
    sweep_k<F, false><<<g, 128, 0, s>>>(T[2], T[1], T[3], rp, cc, dis, N);
    sweep_k<F, false><<<g, 128, 0, s>>>(T[3], T[2], T[4], rp, cc, dis, N);
    combine_k<F, G, false><<<g, 128, 0, s>>>(X, T[0], T[1], T[2], T[3], T[4],
                                             Wk, bias, outb, nullptr, N, relu);
}

// planar lvl0 conv with XCD pinning
template<int F, int G, bool OSTD = false>
static void run_cheb_p(const u16* X, u16* const* T, const float* Wk, const float* bias,
                       int relu, u16* outb, float* outf,
                       const int* rp, const u16* cc, const float* dis, int N, hipStream_t s) {
    unsigned g = (unsigned)cdivu((size_t)B_ * N, 128);
    sweep_p<F, true><<<g, 128, 0, s>>>(X, nullptr, T[0], rp, cc, dis, N);
    sweep_p<F, false><<<g, 128, 0, s>>>(T[0], X, T[1], rp, cc, dis, N);
    sweep_p<F, false><<<g, 128, 0, s>>>(T[1], T[0], T[2], rp, cc, dis, N);
    sweep_p<F, false><<<g, 128, 0, s>>>(T[2], T[1], T[3], rp, cc, dis, N);
    sweep_p<F, false><<<g, 128, 0, s>>>(T[3], T[2], T[4], rp, cc, dis, N);
    combine_k<F, G, OSTD><<<g, 128, 0, s>>>(X, T[0], T[1], T[2], T[3], T[4],
                                            Wk, bias, outb, outf, N, relu);
}

extern "C" void kernel_launch(void* const* d_in, const int* in_sizes, int n_in,
                              void* d_out, int out_size, void* d_ws, size_t ws_size,
                              hipStream_t stream) {
    (void)in_sizes; (void)n_in; (void)out_size; (void)ws_size;
    hipStream_t s = stream;

    static const int NS_[5] = {65536, 16384, 4096, 1024, 256};
    static const int LBa[5] = {LB0, LB1, LB2, LB3, LB4};
    static const int CEa[5] = {CE0, CE1, CE2, CE3, CE4};

    const float* x = (const float*)d_in[0];
    const int* ei[4];
    for (int l = 0; l < 4; ++l) ei[l] = (const int*)d_in[1 + l];
    const int* down_i[4]; const float* down_w[4];
    const int* up_i[4];   const float* up_w[4];
    for (int i = 0; i < 4; ++i) {
        down_i[i] = (const int*)d_in[6 + 4 * i];
        down_w[i] = (const float*)d_in[7 + 4 * i];
        up_i[i]   = (const int*)d_in[8 + 4 * i];
        up_w[i]   = (const float*)d_in[9 + 4 * i];
    }
    const float* encW[4]; const float* encB[4];
    for (int i = 0; i < 4; ++i) {
        encW[i] = (const float*)d_in[22 + 2 * i];
        encB[i] = (const float*)d_in[23 + 2 * i];
    }
    const float* decW[5];
    for (int i = 0; i < 5; ++i) decW[i] = (const float*)d_in[30 + i];
    const float* decB[4];
    for (int i = 0; i < 4; ++i) decB[i] = (const float*)d_in[35 + i];
    const float* enc_w = (const float*)d_in[39];
    const float* enc_b = (const float*)d_in[40];
    const float* dec_w = (const float*)d_in[41];
    const float* dec_b = (const float*)d_in[42];

    // ---- workspace layout (float units) ----
    float* ws = (float*)d_ws;
    size_t off = 0;
    const size_t HSLOT = (size_t)B_ * 65536 * 16 / 2;   // bf16 buffer = 2,097,152 floats (8.4 MB)
    u16* XA = (u16*)(ws + off); off += HSLOT;
    u16* XB = (u16*)(ws + off); off += HSLOT;
    u16* T[5];
    for (int i = 0; i < 5; ++i) { T[i] = (u16*)(ws + off); off += HSLOT; }
    int* cntAll = (int*)(ws + off); off += LB4;   // cnt+cur adjacent -> single memset
    int* curAll = (int*)(ws + off); off += LB4;
    int* partial = (int*)(ws + off); off += LB4;
    int* bsum = (int*)(ws + off); off += 128;
    float* disAll = ws + off; off += LB4;
    int* rowptr[4];
    for (int l = 0; l < 4; ++l) { rowptr[l] = (int*)(ws + off); off += (size_t)NS_[l] + 4; }
    u16* ccolAll = (u16*)(ws + off); off += (CE4 + 1) / 2;
    float* zbuf = ws + off; off += 256;

    // ---- build CSR + norms (consolidated) ----
    hipMemsetAsync(cntAll, 0, (size_t)(2 * LB4) * sizeof(int), s);   // cnt + cur
    cnt_all_kernel<<<cdivu(CE4, TPB), TPB, 0, s>>>(ei[0], ei[1], ei[2], ei[3], cntAll);
    scanA_kernel<<<85, 256, 0, s>>>(cntAll, partial, bsum);
    scanB_kernel<<<1, 128, 0, s>>>(bsum, 85);
    scanC_kernel<<<cdivu(LB4, TPB), TPB, 0, s>>>(partial, bsum, cntAll, disAll,
                                                 rowptr[0], rowptr[1], rowptr[2], rowptr[3]);
    fill_all_kernel<<<cdivu(CE4, TPB), TPB, 0, s>>>(
        ei[0], ei[0] + DEG_ * NS_[0], ei[1], ei[1] + DEG_ * NS_[1],
        ei[2], ei[2] + DEG_ * NS_[2], ei[3], ei[3] + DEG_ * NS_[3],
        rowptr[0], rowptr[1], rowptr[2], rowptr[3], curAll, ccolAll);

    const float* dis[4]; const u16* cc[4];
    for (int l = 0; l < 4; ++l) { dis[l] = disAll + LBa[l]; cc[l] = ccolAll + CEa[l]; }

    // ---- encoder ----
    f2b_kernel<<<cdivu((size_t)B_ * 65536 * 3, TPB), TPB, 0, s>>>(x, XA, B_ * 65536 * 3);
    run_cheb_p<3, 16>(XA, T, encW[0], encB[0], 1, XB, nullptr,
                      rowptr[0], cc[0], dis[0], NS_[0], s);
    pool_down0<<<cdivu((size_t)B_ * NS_[1] * 16, TPB), TPB, 0, s>>>(
        XB, XA, down_i[0], down_w[0], NS_[0], NS_[1], 16);
    run_cheb<16, 16>(XA, T, encW[1], encB[1], 1, XB,
                     rowptr[1], cc[1], dis[1], NS_[1], s);
    pool_kernel<<<cdivu((size_t)B_ * NS_[2] * 16, TPB), TPB, 0, s>>>(
        XB, XA, down_i[1], down_w[1], NS_[2], 16);
    run_cheb<16, 16>(XA, T, encW[2], encB[2], 1, XB,
                     rowptr[2], cc[2], dis[2], NS_[2], s);
    pool_kernel<<<cdivu((size_t)B_ * NS_[3] * 16, TPB), TPB, 0, s>>>(
        XB, XA, down_i[2], down_w[2], NS_[3], 16);
    run_cheb<16, 32>(XA, T, encW[3], encB[3], 1, XB,
                     rowptr[3], cc[3], dis[3], NS_[3], s);
    pool_kernel<<<cdivu((size_t)B_ * NS_[4] * 32, TPB), TPB, 0, s>>>(
        XB, XA, down_i[3], down_w[3], NS_[4], 32);

    // ---- latent ----
    dense_enc_kernel<<<B_ * 64, 256, 0, s>>>(XA, enc_w, enc_b, zbuf);
    dense_dec_kernel<<<cdivu((size_t)B_ * 8192, TPB), TPB, 0, s>>>(zbuf, dec_w, dec_b, XB);

    // ---- decoder ----
    pool_kernel<<<cdivu((size_t)B_ * NS_[3] * 32, TPB), TPB, 0, s>>>(
        XB, XA, up_i[3], up_w[3], NS_[3], 32);
    run_cheb<32, 16>(XA, T, decW[0], decB[0], 1, XB,
                     rowptr[3], cc[3], dis[3], NS_[3], s);
    pool_kernel<<<cdivu((size_t)B_ * NS_[2] * 16, TPB), TPB, 0, s>>>(
        XB, XA, up_i[2], up_w[2], NS_[2], 16);
    run_cheb<16, 16>(XA, T, decW[1], decB[1], 1, XB,
                     rowptr[2], cc[2], dis[2], NS_[2], s);
    pool_kernel<<<cdivu((size_t)B_ * NS_[1] * 16, TPB), TPB, 0, s>>>(
        XB, XA, up_i[1], up_w[1], NS_[1], 16);
    run_cheb<16, 16>(XA, T, decW[2], decB[2], 1, XB,
                     rowptr[1], cc[1], dis[1], NS_[1], s);
    // up-pool to lvl0 planar
    pool_up0<<<cdivu((size_t)B_ * NS_[0] * 16, TPB), TPB, 0, s>>>(
        XB, XA, up_i[0], up_w[0], NS_[0], 16);
    run_cheb_p<16, 16>(XA, T, decW[3], decB[3], 1, XB, nullptr,
                       rowptr[0], cc[0], dis[0], NS_[0], s);
    // final conv: planar -> canonical fp32 [B][N][3] directly
    run_cheb_p<16, 3, true>(XB, T, decW[4], nullptr, 0, nullptr, (float*)d_out,
                            rowptr[0], cc[0], dis[0], NS_[0], s);
}

// Round 13
// 1110.272 us; speedup vs baseline: 1.3046x; 1.3046x over previous
//
#include <hip/hip_runtime.h>

#define TPB 256

static constexpr int B_ = 4;
static constexpr int DEG_ = 16;

using u16 = unsigned short;

// per-row dis[] bases (87040 rows total across levels)
static constexpr int LB0 = 0, LB1 = 65536, LB2 = 81920, LB3 = 86016, LB4 = 87040;
// cumulative edge counts
static constexpr int CE0 = 0, CE1 = 1048576, CE2 = 1310720, CE3 = 1376256, CE4 = 1392640;
// packed scan-key domain: lvl0 = (row<<2)|tile (tile = col>>14), lvl1-3 = per-row
static constexpr int K1 = 262144, K2 = 278528, K3 = 282624, K4 = 283648;  // = 277*1024
static constexpr int KB = 277;

// ---------------- bf16 helpers ----------------

__device__ inline float b2f(u16 u) { return __uint_as_float((unsigned)u << 16); }
__device__ inline u16 f2b(float f) {
    unsigned b = __float_as_uint(f);
    b += 0x7fffu + ((b >> 16) & 1u);   // round-to-nearest-even
    return (u16)(b >> 16);
}

template<int F>
__device__ inline void load_row_bf16(const u16* __restrict__ p, float* v) {
    if constexpr (F % 8 == 0) {
        #pragma unroll
        for (int i = 0; i < F / 8; ++i) {
            uint4 raw = reinterpret_cast<const uint4*>(p)[i];
            unsigned rr[4] = {raw.x, raw.y, raw.z, raw.w};
            #pragma unroll
            for (int k = 0; k < 4; ++k) {
                v[i * 8 + 2 * k]     = __uint_as_float(rr[k] << 16);
                v[i * 8 + 2 * k + 1] = __uint_as_float(rr[k] & 0xffff0000u);
            }
        }
    } else {
        #pragma unroll
        for (int f = 0; f < F; ++f) v[f] = b2f(p[f]);
    }
}

template<int F>
__device__ inline void store_row_bf16(u16* __restrict__ p, const float* v) {
    if constexpr (F % 8 == 0) {
        #pragma unroll
        for (int i = 0; i < F / 8; ++i) {
            uint4 raw;
            unsigned* rr = &raw.x;
            #pragma unroll
            for (int k = 0; k < 4; ++k)
                rr[k] = (unsigned)f2b(v[i * 8 + 2 * k]) |
                        ((unsigned)f2b(v[i * 8 + 2 * k + 1]) << 16);
            reinterpret_cast<uint4*>(p)[i] = raw;
        }
    } else {
        #pragma unroll
        for (int f = 0; f < F; ++f) p[f] = f2b(v[f]);
    }
}

// ---------------- CSR build (column-tiled for lvl0) ----------------

// count per packed key; lvl0 keys (row<<2)|(col>>14) give tile-ordered slots
__global__ void cnt_all_kernel(const int* __restrict__ r0, const int* __restrict__ c0,
                               const int* __restrict__ r1, const int* __restrict__ r2,
                               const int* __restrict__ r3, int* __restrict__ cntAll) {
    int e = blockIdx.x * blockDim.x + threadIdx.x;
    if (e >= CE4) return;
    int key;
    if (e < CE1)      { key = (r0[e] << 2) | (c0[e] >> 14); }
    else if (e < CE2) { key = K1 + r1[e - CE1]; }
    else if (e < CE3) { key = K2 + r2[e - CE2]; }
    else              { key = K3 + r3[e - CE3]; }
    atomicAdd(&cntAll[key], 1);
}

// per-block scan: KB blocks x 1024 elements (256 threads x 4)
__global__ void scanA_kernel(const int* __restrict__ cnt, int* __restrict__ partial,
                             int* __restrict__ bsum) {
    __shared__ int sdata[256];
    int tid = threadIdx.x;
    int base = blockIdx.x * 1024 + tid * 4;
    int v0 = cnt[base], v1 = cnt[base + 1], v2 = cnt[base + 2], v3 = cnt[base + 3];
    int tsum = v0 + v1 + v2 + v3;
    sdata[tid] = tsum;
    __syncthreads();
    for (int ofs = 1; ofs < 256; ofs <<= 1) {
        int x = (tid >= ofs) ? sdata[tid - ofs] : 0;
        __syncthreads();
        sdata[tid] += x;
        __syncthreads();
    }
    int excl = sdata[tid] - tsum;
    partial[base] = excl;         excl += v0;
    partial[base + 1] = excl;     excl += v1;
    partial[base + 2] = excl;     excl += v2;
    partial[base + 3] = excl;
    if (tid == 255) bsum[blockIdx.x] = sdata[255];
}

// exclusive scan of up to 512 block sums, in place
__global__ void scanB_kernel(int* __restrict__ bsum, int nb) {
    __shared__ int s[512];
    int tid = threadIdx.x;
    int v = tid < nb ? bsum[tid] : 0;
    s[tid] = v;
    __syncthreads();
    for (int ofs = 1; ofs < 512; ofs <<= 1) {
        int x = (tid >= ofs) ? s[tid - ofs] : 0;
        __syncthreads();
        s[tid] += x;
        __syncthreads();
    }
    if (tid < nb) bsum[tid] = s[tid] - v;
}

// write per-row rowptrs (lvl0: every 4th key), dis = rsqrt(deg)
__global__ void scanC_kernel(const int* __restrict__ partial, const int* __restrict__ bsum,
                             const int* __restrict__ cnt, float* __restrict__ disAll,
                             int* __restrict__ rp0, int* __restrict__ rp1,
                             int* __restrict__ rp2, int* __restrict__ rp3) {
    int i = blockIdx.x * blockDim.x + threadIdx.x;
    if (i >= K4) return;
    int g = partial[i] + bsum[i >> 10];
    if (i < K1) {
        if ((i & 3) == 0) {
            int r = i >> 2;
            rp0[r] = g;   // lvl0 edge base = 0
            int deg = cnt[i] + cnt[i + 1] + cnt[i + 2] + cnt[i + 3];
            disAll[LB0 + r] = deg > 0 ? rsqrtf((float)deg) : 0.f;
        }
    } else if (i < K2) {
        int r = i - K1;
        rp1[r] = g - CE1;
        int c = cnt[i];
        disAll[LB1 + r] = c > 0 ? rsqrtf((float)c) : 0.f;
    } else if (i < K3) {
        int r = i - K2;
        rp2[r] = g - CE2;
        int c = cnt[i];
        disAll[LB2 + r] = c > 0 ? rsqrtf((float)c) : 0.f;
    } else {
        int r = i - K3;
        rp3[r] = g - CE3;
        int c = cnt[i];
        disAll[LB3 + r] = c > 0 ? rsqrtf((float)c) : 0.f;
    }
    if (i == 0) {
        rp0[65536] = CE1 - CE0;
        rp1[16384] = CE2 - CE1;
        rp2[4096]  = CE3 - CE2;
        rp3[1024]  = CE4 - CE3;
    }
}

// scatter u16 column indices into tile-ordered CSR slots.
// global scan value of a key == its slot base in ccolAll (domains match 1:1).
__global__ void fill_all_kernel(const int* __restrict__ r0, const int* __restrict__ c0,
                                const int* __restrict__ r1, const int* __restrict__ c1,
                                const int* __restrict__ r2, const int* __restrict__ c2,
                                const int* __restrict__ r3, const int* __restrict__ c3,
                                const int* __restrict__ partial, const int* __restrict__ bsum,
                                int* __restrict__ curAll, u16* __restrict__ ccolAll) {
    int e = blockIdx.x * blockDim.x + threadIdx.x;
    if (e >= CE4) return;
    int key, c;
    if (e < CE1)      { c = c0[e];       key = (r0[e] << 2) | (c >> 14); }
    else if (e < CE2) { int le = e - CE1; c = c1[le]; key = K1 + r1[le]; }
    else if (e < CE3) { int le = e - CE2; c = c2[le]; key = K2 + r2[le]; }
    else              { int le = e - CE3; c = c3[le]; key = K3 + r3[le]; }
    int slot = partial[key] + bsum[key >> 10] + atomicAdd(&curAll[key], 1);
    ccolAll[slot] = (u16)c;
}

// ---------------- fp32 [B][N][3] -> bf16 [N][B][3] transpose-convert ----------------

__global__ void f2b_tr_kernel(const float* __restrict__ in, u16* __restrict__ out, int N) {
    int t = blockIdx.x * blockDim.x + threadIdx.x;   // output-ordered
    if (t >= B_ * N * 3) return;
    int f = t % 3;
    int nb = t / 3;
    int b = nb & 3;
    int n = nb >> 2;
    out[t] = f2b(in[((size_t)b * N + n) * 3 + f]);
}

// ---------------- Chebyshev T-sweep (no GEMM) ----------------
// Batch-interleaved [N][B][F]; thread t -> (r=t>>2, b=t&3).
// FIRST: T1 = L x (alpha 1, no self term); else: Tk = 2 L T_{k-1} - T_{k-2}
// lvl0 CSR edge lists are column-tile-ordered -> loose machine-wide lockstep on a
// ~2.1MB source tile at a time (L2-resident) without any kernel change.
template<int F, bool FIRST>
__global__ __launch_bounds__(128) void sweep_k(
    const u16* __restrict__ gsrc, const u16* __restrict__ selfp, u16* __restrict__ dst,
    const int* __restrict__ rowptr, const u16* __restrict__ ccol,
    const float* __restrict__ dis, int N)
{
    int t = blockIdx.x * 128 + (int)threadIdx.x;
    if (t >= B_ * N) return;
    int r = t >> 2;
    int b = t & 3;

    float tv[F];
    if constexpr (FIRST) {
        #pragma unroll
        for (int f = 0; f < F; ++f) tv[f] = 0.f;
    } else {
        float sv[F];
        load_row_bf16<F>(selfp + (size_t)t * F, sv);
        #pragma unroll
        for (int f = 0; f < F; ++f) tv[f] = -sv[f];
    }
    const float scale = (FIRST ? 1.0f : 2.0f) * dis[r];
    int beg = rowptr[r], end = rowptr[r + 1];
    for (int e = beg; e < end; ++e) {
        int c = (int)ccol[e];
        float w = scale * dis[c];
        float gv[F];
        load_row_bf16<F>(gsrc + (size_t)((c << 2) | b) * F, gv);
        #pragma unroll
        for (int f = 0; f < F; ++f) tv[f] += w * gv[f];
    }
    store_row_bf16<F>(dst + (size_t)t * F, tv);
}

// ---------------- streaming combine: out = sum_k T_k @ W_k (+bias, relu) ----------------
// Pure streaming reads, acc in registers. No gather here (round-9 lesson: fusing a
// gather into this wide-accumulator epilogue blows VGPR to 256 and kills occupancy).
template<int F, int G, bool OSTD>
__global__ __launch_bounds__(128) void combine_k(
    const u16* __restrict__ T0, const u16* __restrict__ T1, const u16* __restrict__ T2,
    const u16* __restrict__ T3, const u16* __restrict__ T4, const u16* __restrict__ T5,
    const float* __restrict__ W6, const float* __restrict__ bias,
    u16* __restrict__ outb, float* __restrict__ outf, int N, int relu)
{
    __shared__ float sW[6 * F * G];
    for (int i = threadIdx.x; i < 6 * F * G; i += 128) sW[i] = W6[i];
    __syncthreads();
    int t = blockIdx.x * 128 + (int)threadIdx.x;
    if (t >= B_ * N) return;

    float acc[G];
    #pragma unroll
    for (int g = 0; g < G; ++g) acc[g] = 0.f;

    const u16* Ts[6] = {T0, T1, T2, T3, T4, T5};
    #pragma unroll
    for (int k = 0; k < 6; ++k) {
        float tv[F];
        load_row_bf16<F>(Ts[k] + (size_t)t * F, tv);
        const float* w = sW + k * F * G;
        #pragma unroll
        for (int f = 0; f < F; ++f) {
            float x = tv[f];
            #pragma unroll
            for (int g = 0; g < G; ++g) acc[g] += x * w[f * G + g];
        }
    }
    if (bias) {
        #pragma unroll
        for (int g = 0; g < G; ++g) acc[g] += bias[g];
    }
    if (relu) {
        #pragma unroll
        for (int g = 0; g < G; ++g) acc[g] = fmaxf(acc[g], 0.f);
    }
    if (OSTD) {
        int r = t >> 2, b = t & 3;
        float* orow = outf + ((size_t)b * N + r) * G;
        #pragma unroll
        for (int g = 0; g < G; ++g) orow[g] = acc[g];
    } else {
        store_row_bf16<G>(outb + (size_t)t * G, acc);
    }
}

// ---------------- pool / dense (bf16 interleaved [N][B][F]) ----------------

__global__ void pool_kernel(const u16* __restrict__ in, u16* __restrict__ out,
                            const int* __restrict__ idx, const float* __restrict__ w,
                            int Nout, int F) {
    int t = blockIdx.x * blockDim.x + threadIdx.x;
    if (t >= B_ * Nout * F) return;
    int f = t % F;
    int nb = t / F;
    int b = nb & 3;
    int n = nb >> 2;
    float acc = 0.f;
    for (int k = 0; k < 3; ++k) {
        int src = idx[n * 3 + k];
        acc += w[n * 3 + k] * b2f(in[(size_t)((src << 2) | b) * F + f]);
    }
    out[t] = f2b(acc);
}

// h bf16 interleaved [256][4][32]; logical h[b, i], i = n*32+f
__global__ void dense_enc_kernel(const u16* __restrict__ h, const float* __restrict__ W,
                                 const float* __restrict__ bias, float* __restrict__ z) {
    int b = blockIdx.x >> 6;
    int g = blockIdx.x & 63;
    int tid = threadIdx.x;
    float acc = 0.f;
    for (int i = tid; i < 8192; i += 256) {
        int n = i >> 5, f = i & 31;
        acc += b2f(h[(((size_t)n << 2) | b) * 32 + f]) * W[(size_t)i * 64 + g];
    }
    __shared__ float red[256];
    red[tid] = acc;
    __syncthreads();
    for (int sft = 128; sft > 0; sft >>= 1) {
        if (tid < sft) red[tid] += red[tid + sft];
        __syncthreads();
    }
    if (tid == 0) z[b * 64 + g] = fmaxf(red[0] + bias[g], 0.f);
}

// out bf16 interleaved [256][4][32]
__global__ void dense_dec_kernel(const float* __restrict__ z, const float* __restrict__ W,
                                 const float* __restrict__ bias, u16* __restrict__ out) {
    int t = blockIdx.x * blockDim.x + threadIdx.x;
    if (t >= B_ * 8192) return;
    int b = t / 8192, j = t % 8192;
    float acc = bias[j];
    for (int k = 0; k < 64; ++k) acc += z[b * 64 + k] * W[(size_t)k * 8192 + j];
    int n = j >> 5, f = j & 31;
    out[(((size_t)n << 2) | b) * 32 + f] = f2b(fmaxf(acc, 0.f));
}

// ---------------- host ----------------

static inline unsigned cdivu(size_t a, size_t b) { return (unsigned)((a + b - 1) / b); }

template<int F, int G, bool OSTD = false>
static void run_cheb(const u16* X, u16* const* T, const float* Wk, const float* bias,
                     int relu, u16* outb, float* outf,
                     const int* rp, const u16* cc, const float* dis, int N, hipStream_t s) {
    unsigned g = (unsigned)cdivu((size_t)B_ * N, 128);
    sweep_k<F, true><<<g, 128, 0, s>>>(X, nullptr, T[0], rp, cc, dis, N);
    sweep_k<F, false><<<g, 128, 0, s>>>(T[0], X, T[1], rp, cc, dis, N);
    sweep_k<F, false><<<g, 128, 0, s>>>(T[1], T[0], T[2], rp, cc, dis, N);
    sweep_k<F, false><<<g, 128, 0, s>>>(T[2], T[1], T[3], rp, cc, dis, N);
    sweep_k<F, false><<<g, 128, 0, s>>>(T[3], T[2], T[4], rp, cc, dis, N);
    combine_k<F, G, OSTD><<<g, 128, 0, s>>>(X, T[0], T[1], T[2], T[3], T[4],
                                            Wk, bias, outb, outf, N, relu);
}

extern "C" void kernel_launch(void* const* d_in, const int* in_sizes, int n_in,
                              void* d_out, int out_size, void* d_ws, size_t ws_size,
                              hipStream_t stream) {
    (void)in_sizes; (void)n_in; (void)out_size; (void)ws_size;
    hipStream_t s = stream;

    static const int NS_[5] = {65536, 16384, 4096, 1024, 256};
    static const int LBa[5] = {LB0, LB1, LB2, LB3, LB4};
    static const int CEa[5] = {CE0, CE1, CE2, CE3, CE4};

    const float* x = (const float*)d_in[0];
    const int* ei[4];
    for (int l = 0; l < 4; ++l) ei[l] = (const int*)d_in[1 + l];
    const int* down_i[4]; const float* down_w[4];
    const int* up_i[4];   const float* up_w[4];
    for (int i = 0; i < 4; ++i) {
        down_i[i] = (const int*)d_in[6 + 4 * i];
        down_w[i] = (const float*)d_in[7 + 4 * i];
        up_i[i]   = (const int*)d_in[8 + 4 * i];
        up_w[i]   = (const float*)d_in[9 + 4 * i];
    }
    const float* encW[4]; const float* encB[4];
    for (int i = 0; i < 4; ++i) {
        encW[i] = (const float*)d_in[22 + 2 * i];
        encB[i] = (const float*)d_in[23 + 2 * i];
    }
    const float* decW[5];
    for (int i = 0; i < 5; ++i) decW[i] = (const float*)d_in[30 + i];
    const float* decB[4];
    for (int i = 0; i < 4; ++i) decB[i] = (const float*)d_in[35 + i];
    const float* enc_w = (const float*)d_in[39];
    const float* enc_b = (const float*)d_in[40];
    const float* dec_w = (const float*)d_in[41];
    const float* dec_b = (const float*)d_in[42];

    // ---- workspace layout (float units) ----
    float* ws = (float*)d_ws;
    size_t off = 0;
    const size_t HSLOT = (size_t)B_ * 65536 * 16 / 2;   // bf16 buffer = 2,097,152 floats (8.4 MB)
    u16* XA = (u16*)(ws + off); off += HSLOT;
    u16* XB = (u16*)(ws + off); off += HSLOT;
    u16* T[5];
    for (int i = 0; i < 5; ++i) { T[i] = (u16*)(ws + off); off += HSLOT; }
    int* cntAll = (int*)(ws + off); off += K4;   // cnt + cur adjacent -> single memset
    int* curAll = (int*)(ws + off); off += K4;
    int* partial = (int*)(ws + off); off += K4;
    int* bsum = (int*)(ws + off); off += 512;
    float* disAll = ws + off; off += LB4;
    int* rowptr[4];
    for (int l = 0; l < 4; ++l) { rowptr[l] = (int*)(ws + off); off += (size_t)NS_[l] + 4; }
    u16* ccolAll = (u16*)(ws + off); off += (CE4 + 1) / 2;
    float* zbuf = ws + off; off += 256;

    // ---- build CSR (lvl0 column-tiled) + norms: 5 dispatches + 1 memset ----
    hipMemsetAsync(cntAll, 0, (size_t)(2 * K4) * sizeof(int), s);   // cnt + cur
    cnt_all_kernel<<<cdivu(CE4, TPB), TPB, 0, s>>>(
        ei[0], ei[0] + DEG_ * NS_[0], ei[1], ei[2], ei[3], cntAll);
    scanA_kernel<<<KB, 256, 0, s>>>(cntAll, partial, bsum);
    scanB_kernel<<<1, 512, 0, s>>>(bsum, KB);
    scanC_kernel<<<cdivu(K4, TPB), TPB, 0, s>>>(partial, bsum, cntAll, disAll,
                                                rowptr[0], rowptr[1], rowptr[2], rowptr[3]);
    fill_all_kernel<<<cdivu(CE4, TPB), TPB, 0, s>>>(
        ei[0], ei[0] + DEG_ * NS_[0], ei[1], ei[1] + DEG_ * NS_[1],
        ei[2], ei[2] + DEG_ * NS_[2], ei[3], ei[3] + DEG_ * NS_[3],
        partial, bsum, curAll, ccolAll);

    const float* dis[4]; const u16* cc[4];
    for (int l = 0; l < 4; ++l) { dis[l] = disAll + LBa[l]; cc[l] = ccolAll + CEa[l]; }

    // ---- encoder ----
    f2b_tr_kernel<<<cdivu((size_t)B_ * 65536 * 3, TPB), TPB, 0, s>>>(x, XA, 65536);
    run_cheb<3, 16>(XA, T, encW[0], encB[0], 1, XB, nullptr,
                    rowptr[0], cc[0], dis[0], NS_[0], s);
    pool_kernel<<<cdivu((size_t)B_ * NS_[1] * 16, TPB), TPB, 0, s>>>(
        XB, XA, down_i[0], down_w[0], NS_[1], 16);
    run_cheb<16, 16>(XA, T, encW[1], encB[1], 1, XB, nullptr,
                     rowptr[1], cc[1], dis[1], NS_[1], s);
    pool_kernel<<<cdivu((size_t)B_ * NS_[2] * 16, TPB), TPB, 0, s>>>(
        XB, XA, down_i[1], down_w[1], NS_[2], 16);
    run_cheb<16, 16>(XA, T, encW[2], encB[2], 1, XB, nullptr,
                     rowptr[2], cc[2], dis[2], NS_[2], s);
    pool_kernel<<<cdivu((size_t)B_ * NS_[3] * 16, TPB), TPB, 0, s>>>(
        XB, XA, down_i[2], down_w[2], NS_[3], 16);
    run_cheb<16, 32>(XA, T, encW[3], encB[3], 1, XB, nullptr,
                     rowptr[3], cc[3], dis[3], NS_[3], s);
    pool_kernel<<<cdivu((size_t)B_ * NS_[4] * 32, TPB), TPB, 0, s>>>(
        XB, XA, down_i[3], down_w[3], NS_[4], 32);

    // ---- latent ----
    dense_enc_kernel<<<B_ * 64, 256, 0, s>>>(XA, enc_w, enc_b, zbuf);
    dense_dec_kernel<<<cdivu((size_t)B_ * 8192, TPB), TPB, 0, s>>>(zbuf, dec_w, dec_b, XB);

    // ---- decoder ----
    pool_kernel<<<cdivu((size_t)B_ * NS_[3] * 32, TPB), TPB, 0, s>>>(
        XB, XA, up_i[3], up_w[3], NS_[3], 32);
    run_cheb<32, 16>(XA, T, decW[0], decB[0], 1, XB, nullptr,
                     rowptr[3], cc[3], dis[3], NS_[3], s);
    pool_kernel<<<cdivu((size_t)B_ * NS_[2] * 16, TPB), TPB, 0, s>>>(
        XB, XA, up_i[2], up_w[2], NS_[2], 16);
    run_cheb<16, 16>(XA, T, decW[1], decB[1], 1, XB, nullptr,
                     rowptr[2], cc[2], dis[2], NS_[2], s);
    pool_kernel<<<cdivu((size_t)B_ * NS_[1] * 16, TPB), TPB, 0, s>>>(
        XB, XA, up_i[1], up_w[1], NS_[1], 16);
    run_cheb<16, 16>(XA, T, decW[2], decB[2], 1, XB, nullptr,
                     rowptr[1], cc[1], dis[1], NS_[1], s);
    pool_kernel<<<cdivu((size_t)B_ * NS_[0] * 16, TPB), TPB, 0, s>>>(
        XB, XA, up_i[0], up_w[0], NS_[0], 16);
    run_cheb<16, 16>(XA, T, decW[3], decB[3], 1, XB, nullptr,
                     rowptr[0], cc[0], dis[0], NS_[0], s);
    // final conv: 16 -> 3, no bias/relu, fp32 -> d_out in canonical [B][N][3]
    run_cheb<16, 3, true>(XB, T, decW[4], nullptr, 0, nullptr, (float*)d_out,
                          rowptr[0], cc[0], dis[0], NS_[0], s);
}